// Round 6
// baseline (377.842 us; speedup 1.0000x reference)
//
#include <hip/hip_runtime.h>
#include <hip/hip_fp16.h>

// SpMM: out[r,:] = sum_{k: rows[k]==r} values[k] * weight[cols[k],:]  + bias
// R6: gather f32 weight DIRECTLY (no fp16 convert pass — it cost a full
// 307MB stream, 74us, while slicing already made accum L2-resident).
// Counting-sort nnz by row -> (col,val) pairs; per-row sort by col so all
// resident waves sweep weight front-to-back in lockstep; XCD column-QUARTER
// slicing (quarter = blockIdx&3, round-robin %8 block->XCD => quarter j on
// XCDs {j,j+4}) keeps the per-XCD sweep window ~2.3MB < 4MiB L2.

// ---- Row histogram ----
__global__ void count_rows_kernel(const int* __restrict__ rows, int* __restrict__ counts, int nnz) {
    int i = blockIdx.x * blockDim.x + threadIdx.x;
    if (i < nnz) atomicAdd(&counts[rows[i]], 1);
}

// ---- Exclusive scan over counts (1 block); writes offsets AND cursor ----
__global__ void scan_kernel(const int* __restrict__ counts, int* __restrict__ offsets,
                            int* __restrict__ cursor, int n_rows) {
    __shared__ int partial[256];
    const int t = threadIdx.x;
    const int per = (n_rows + 255) / 256;
    const int base = t * per;
    int sum = 0;
    for (int j = 0; j < per; ++j) {
        int idx = base + j;
        if (idx < n_rows) sum += counts[idx];
    }
    partial[t] = sum;
    __syncthreads();
    for (int off = 1; off < 256; off <<= 1) {
        int v = 0;
        if (t >= off) v = partial[t - off];
        __syncthreads();
        if (t >= off) partial[t] += v;
        __syncthreads();
    }
    int run = (t == 0) ? 0 : partial[t - 1];
    for (int j = 0; j < per; ++j) {
        int idx = base + j;
        if (idx < n_rows) {
            offsets[idx] = run;
            cursor[idx] = run;
            run += counts[idx];
        }
    }
    if (t == 255) offsets[n_rows] = run;
}

// ---- Scatter nnz into row buckets as (col,val) pairs ----
__global__ void scatter_pairs_kernel(const int* __restrict__ rows, const int* __restrict__ cols,
                                     const float* __restrict__ values, int* __restrict__ cursor,
                                     int2* __restrict__ pairs, int nnz) {
    int i = blockIdx.x * blockDim.x + threadIdx.x;
    if (i < nnz) {
        int p = atomicAdd(&cursor[rows[i]], 1);
        pairs[p] = make_int2(cols[i], __float_as_int(values[i]));
    }
}

// ---- Per-row bitonic sort by col (PERF-ONLY: accum is order-independent) ----
__global__ __launch_bounds__(256) void sort_rows_kernel(const int* __restrict__ offsets,
                                                        int2* __restrict__ pairs) {
    const int row = blockIdx.x;
    const int start = offsets[row];
    const int n = offsets[row + 1] - start;
    if (n > 256) return;               // vanishingly rare; sort is optional
    __shared__ unsigned long long key[256];
    const int t = threadIdx.x;
    if (t < n) {
        int2 e = pairs[start + t];
        key[t] = ((unsigned long long)(unsigned)e.x << 32) | (unsigned)e.y;
    } else {
        key[t] = ~0ull;                 // sentinel sorts to end
    }
    for (int k = 2; k <= 256; k <<= 1) {
        for (int j = k >> 1; j > 0; j >>= 1) {
            __syncthreads();
            int l = t ^ j;
            if (l > t) {
                unsigned long long a = key[t];
                unsigned long long b = key[l];
                bool asc = (t & k) == 0;
                if (asc ? (a > b) : (a < b)) {
                    key[t] = b;
                    key[l] = a;
                }
            }
        }
    }
    __syncthreads();
    if (t < n) {
        pairs[start + t] = make_int2((int)(key[t] >> 32),
                                     (int)(unsigned)(key[t] & 0xffffffffull));
    }
}

// ---- Accumulate: block = 4 rows x ONE column quarter; quarter = blockIdx&3 ----
// Quarter j lands on XCDs {j, j+4} (round-robin %8): per-XCD L2 caches only a
// 512B/row slice -> sorted-sweep window ~2.3MB, L2-resident. Lane covers 2 f32
// cols (8B float2 gather); unroll-8 nnz loop for MLP. 4096 blocks.
__global__ __launch_bounds__(256) void accum_f32_kernel(
    const float* __restrict__ weight, const float* __restrict__ bias,
    const int* __restrict__ offsets, const int2* __restrict__ pairs,
    float* __restrict__ out, int out_f) {
    const int wave = threadIdx.x >> 6;
    const int lane = threadIdx.x & 63;
    const int quarter = blockIdx.x & 3;
    const int row = (blockIdx.x >> 2) * 4 + wave;
    const int start = offsets[row];
    const int end   = offsets[row + 1];

    const int colbase = quarter * 128 + lane * 2;   // 2 f32 cols per lane
    const float2* wbase = (const float2*)weight;
    const int fidx = colbase >> 1;                  // float2 index within row
    const int frow = out_f >> 1;                    // float2s per row (=256)

    float acc0 = 0.f, acc1 = 0.f;

    constexpr int U = 8;
    int p = start;
    for (; p + U <= end; p += U) {
        int2 e[U];
#pragma unroll
        for (int u = 0; u < U; ++u) e[u] = pairs[p + u];
        float2 w[U];
#pragma unroll
        for (int u = 0; u < U; ++u)
            w[u] = wbase[(long long)e[u].x * frow + fidx];
#pragma unroll
        for (int u = 0; u < U; ++u) {
            float v = __int_as_float(e[u].y);
            acc0 += v * w[u].x;
            acc1 += v * w[u].y;
        }
    }
    for (; p < end; ++p) {
        int2 e0 = pairs[p];
        float v0 = __int_as_float(e0.y);
        float2 w0 = wbase[(long long)e0.x * frow + fidx];
        acc0 += v0 * w0.x;
        acc1 += v0 * w0.y;
    }

    float2 bv = *(const float2*)(bias + colbase);
    float2 o = make_float2(acc0 + bv.x, acc1 + bv.y);
    *(float2*)(out + (long long)row * out_f + colbase) = o;
}

// ================= Fallback path (generic shapes): f32 atomic-free scheme =================
__global__ void scatter_kernel(const int* __restrict__ rows, int* __restrict__ cursor,
                               int* __restrict__ perm, int nnz) {
    int i = blockIdx.x * blockDim.x + threadIdx.x;
    if (i < nnz) {
        int p = atomicAdd(&cursor[rows[i]], 1);
        perm[p] = i;
    }
}
__global__ void accum_kernel(const float* __restrict__ values, const float* __restrict__ weight,
                             const float* __restrict__ bias, const int* __restrict__ cols,
                             const int* __restrict__ offsets, const int* __restrict__ perm,
                             float* __restrict__ out, int out_f) {
    const int r = blockIdx.x;
    const int start = offsets[r];
    const int end = offsets[r + 1];
    const int step = blockDim.x * 4;
    for (int base = threadIdx.x * 4; base < out_f; base += step) {
        float4 acc = make_float4(0.f, 0.f, 0.f, 0.f);
        for (int p = start; p < end; ++p) {
            int k = perm[p];
            float v = values[k];
            long long c = cols[k];
            float4 w = *(const float4*)(weight + c * (long long)out_f + base);
            acc.x += v * w.x; acc.y += v * w.y; acc.z += v * w.z; acc.w += v * w.w;
        }
        float4 b = *(const float4*)(bias + base);
        acc.x += b.x; acc.y += b.y; acc.z += b.z; acc.w += b.w;
        *(float4*)(out + (long long)r * out_f + base) = acc;
    }
}

static size_t align_up(size_t x, size_t a) { return (x + a - 1) & ~(a - 1); }

extern "C" void kernel_launch(void* const* d_in, const int* in_sizes, int n_in,
                              void* d_out, int out_size, void* d_ws, size_t ws_size,
                              hipStream_t stream) {
    const float* values = (const float*)d_in[0];
    const float* weight = (const float*)d_in[1];
    const float* bias   = (const float*)d_in[2];
    const int*   rows   = (const int*)d_in[3];
    const int*   cols   = (const int*)d_in[4];

    const int nnz = in_sizes[0];
    const int out_f = in_sizes[2];
    const int n_rows = out_size / out_f;
    float* out = (float*)d_out;

    // ws layout: counts[n_rows] | offsets[n_rows+1] | cursor[n_rows] | pairs[nnz]
    size_t off_counts = 0;
    size_t off_offsets = off_counts + (size_t)n_rows * sizeof(int);
    size_t off_cursor = off_offsets + (size_t)(n_rows + 1) * sizeof(int);
    size_t off_pairs = align_up(off_cursor + (size_t)n_rows * sizeof(int), 256);
    size_t need = off_pairs + (size_t)nnz * sizeof(int2);

    if (ws_size >= need && out_f == 512 && (n_rows % 4) == 0) {
        char* ws = (char*)d_ws;
        int* counts = (int*)(ws + off_counts);
        int* offsets = (int*)(ws + off_offsets);
        int* cursor = (int*)(ws + off_cursor);
        int2* pairs = (int2*)(ws + off_pairs);

        hipMemsetAsync(counts, 0, (size_t)n_rows * sizeof(int), stream);

        int blocks = (nnz + 255) / 256;
        count_rows_kernel<<<blocks, 256, 0, stream>>>(rows, counts, nnz);
        scan_kernel<<<1, 256, 0, stream>>>(counts, offsets, cursor, n_rows);
        scatter_pairs_kernel<<<blocks, 256, 0, stream>>>(rows, cols, values, cursor,
                                                         pairs, nnz);
        sort_rows_kernel<<<n_rows, 256, 0, stream>>>(offsets, pairs);
        // block = 4 rows x 1 column-quarter; quarters cycle with blockIdx&3
        accum_f32_kernel<<<(n_rows / 4) * 4, 256, 0, stream>>>(weight, bias, offsets,
                                                               pairs, out, out_f);
    } else {
        // generic fallback: counts | offsets | cursor | perm
        int* counts = (int*)d_ws;
        int* offsets = counts + n_rows;
        int* cursor = offsets + n_rows + 1;
        int* perm = cursor + n_rows;
        hipMemsetAsync(counts, 0, (size_t)n_rows * sizeof(int), stream);
        int blocks = (nnz + 255) / 256;
        count_rows_kernel<<<blocks, 256, 0, stream>>>(rows, counts, nnz);
        scan_kernel<<<1, 256, 0, stream>>>(counts, offsets, cursor, n_rows);
        scatter_kernel<<<blocks, 256, 0, stream>>>(rows, cursor, perm, nnz);
        accum_kernel<<<n_rows, 128, 0, stream>>>(values, weight, bias, cols,
                                                 offsets, perm, out, out_f);
    }
}